// Round 5
// baseline (11330.711 us; speedup 1.0000x reference)
//
#include <hip/hip_runtime.h>

#define N_PTS 16384
#define M_PTS 4096
#define D_INF 64
#define D_OUTF 128
#define KNN 16
#define DF 67   // 3 + 64
#define NCH 256      // 256 chunks x 64 points (Morton-sorted)
#define NCELL 512    // 8x8x8 Morton cells

// ---------------- squared norms of p, numpy op order ----------------
__global__ __launch_bounds__(256) void sp_kernel(const float* __restrict__ p,
                                                 float* __restrict__ spn) {
  int j = blockIdx.x * 256 + threadIdx.x;
  float a = p[3 * j], b = p[3 * j + 1], c = p[3 * j + 2];
  spn[j] = __fadd_rn(__fadd_rn(__fmul_rn(a, a), __fmul_rn(b, b)), __fmul_rn(c, c));
}

// ---------------- spatial binning: 9-bit Morton cell id ----------------
__device__ __forceinline__ int cell_of(float x, float y, float z) {
  int qx = (int)floorf((x + 6.0f) * 0.6666667f);
  int qy = (int)floorf((y + 6.0f) * 0.6666667f);
  int qz = (int)floorf((z + 6.0f) * 0.6666667f);
  qx = min(max(qx, 0), 7); qy = min(max(qy, 0), 7); qz = min(max(qz, 0), 7);
  return (qx & 1) | ((qy & 1) << 1) | ((qz & 1) << 2)
       | ((qx & 2) << 2) | ((qy & 2) << 3) | ((qz & 2) << 4)
       | ((qx & 4) << 4) | ((qy & 4) << 5) | ((qz & 4) << 6);
}

__global__ __launch_bounds__(256) void hist_kernel(const float* __restrict__ p,
                                                   int* __restrict__ hist) {
  int j = blockIdx.x * 256 + threadIdx.x;
  atomicAdd(&hist[cell_of(p[3 * j], p[3 * j + 1], p[3 * j + 2])], 1);
}

__global__ __launch_bounds__(NCELL) void scan_kernel(const int* __restrict__ hist,
                                                     int* __restrict__ cellptr) {
  __shared__ int sh[NCELL];
  int t = threadIdx.x;
  int self = hist[t];
  sh[t] = self;
  __syncthreads();
  for (int off = 1; off < NCELL; off <<= 1) {
    int v = sh[t];
    int a = (t >= off) ? sh[t - off] : 0;
    __syncthreads();
    sh[t] = v + a;
    __syncthreads();
  }
  cellptr[t] = sh[t] - self;  // exclusive prefix
}

// scatter into Morton order; w carries the original index as bits
__global__ __launch_bounds__(256) void scatter_kernel(const float* __restrict__ p,
                                                      int* __restrict__ cellptr,
                                                      float4* __restrict__ sp4) {
  int j = blockIdx.x * 256 + threadIdx.x;
  float x = p[3 * j], y = p[3 * j + 1], z = p[3 * j + 2];
  int pos = atomicAdd(&cellptr[cell_of(x, y, z)], 1);
  sp4[pos] = make_float4(x, y, z, __int_as_float(j));
}

// per-chunk bbox of the 64 sorted points
__global__ __launch_bounds__(64) void bbox_kernel(const float4* __restrict__ sp4,
                                                  float* __restrict__ chunkbb) {
  int c = blockIdx.x;
  int lane = threadIdx.x;
  float4 q = sp4[(c << 6) + lane];
  float mnx = q.x, mxx = q.x, mny = q.y, mxy = q.y, mnz = q.z, mxz = q.z;
#pragma unroll
  for (int off = 32; off >= 1; off >>= 1) {
    mnx = fminf(mnx, __shfl_xor(mnx, off)); mxx = fmaxf(mxx, __shfl_xor(mxx, off));
    mny = fminf(mny, __shfl_xor(mny, off)); mxy = fmaxf(mxy, __shfl_xor(mxy, off));
    mnz = fminf(mnz, __shfl_xor(mnz, off)); mxz = fmaxf(mxz, __shfl_xor(mxz, off));
  }
  if (lane == 0) {
    chunkbb[8 * c + 0] = mnx; chunkbb[8 * c + 1] = mny; chunkbb[8 * c + 2] = mnz;
    chunkbb[8 * c + 3] = mxx; chunkbb[8 * c + 4] = mxy; chunkbb[8 * c + 5] = mxz;
  }
}

// ---------------- FPS with chunk pruning: single block, 1024 thr ----------
// dd update skipped for a chunk only when lb2(center,bbox)*0.9999 >= dd_max:
// then every computed d >= dd[j] and min(dd,d)==dd bit-exactly => exact skip.
__global__ __launch_bounds__(1024) void fps2_kernel(const float* __restrict__ p,
                                                    const float4* __restrict__ sp4,
                                                    const float* __restrict__ chunkbb,
                                                    float* __restrict__ dd,
                                                    int* __restrict__ sidx,
                                                    float* __restrict__ np_out) {
  const int t = threadIdx.x;
  const int lane = t & 63;
  const int wave = t >> 6;
  __shared__ float s_bb[NCH * 9];                  // stride 9: bank-friendly
  __shared__ float s_ddmax[NCH];
  __shared__ unsigned long long s_key[NCH];        // persistent (ddmax, ~oidx)
  __shared__ unsigned short s_dirty[NCH];
  __shared__ int s_cnt[2];
  __shared__ unsigned long long s_wkey[2][16];

  for (int j = t; j < N_PTS; j += 1024) dd[j] = INFINITY;
  if (t < NCH) {
#pragma unroll
    for (int k = 0; k < 6; ++k) s_bb[9 * t + k] = chunkbb[8 * t + k];
    s_ddmax[t] = INFINITY;
  }
  float lx = p[0], ly = p[1], lz = p[2];  // first center = point 0
  if (t == 0) {
    s_cnt[0] = 0; s_cnt[1] = 0;
    sidx[0] = 0;
    np_out[0] = lx; np_out[1] = ly; np_out[2] = lz;
  }
  __syncthreads();

  for (int i = 1; i < M_PTS; ++i) {
    const int buf = i & 1;
    // phase 1: chunk prune test
    if (t < NCH) {
      float ax = fmaxf(fmaxf(__fsub_rn(s_bb[9 * t + 0], lx),
                             __fsub_rn(lx, s_bb[9 * t + 3])), 0.f);
      float ay = fmaxf(fmaxf(__fsub_rn(s_bb[9 * t + 1], ly),
                             __fsub_rn(ly, s_bb[9 * t + 4])), 0.f);
      float az = fmaxf(fmaxf(__fsub_rn(s_bb[9 * t + 2], lz),
                             __fsub_rn(lz, s_bb[9 * t + 5])), 0.f);
      float lb2 = __fadd_rn(__fadd_rn(__fmul_rn(ax, ax), __fmul_rn(ay, ay)),
                            __fmul_rn(az, az));
      if (__fmul_rn(lb2, 0.9999f) < s_ddmax[t]) {
        int pos = atomicAdd(&s_cnt[buf], 1);
        s_dirty[pos] = (unsigned short)t;
      }
    }
    __syncthreads();  // B1: dirty list ready
    const int cnt = s_cnt[buf];
    if (t == 0) s_cnt[buf ^ 1] = 0;  // prep next iter's counter
    // phase 2: update dirty chunks, one wave per chunk
    const int rounds = (cnt + 15) >> 4;
    for (int r = 0; r < rounds; ++r) {
      int li = (r << 4) + wave;
      if (li < cnt) {
        int c = s_dirty[li];
        int pos = (c << 6) + lane;
        float4 q = sp4[pos];
        float dx = __fsub_rn(q.x, lx);
        float dy = __fsub_rn(q.y, ly);
        float dz = __fsub_rn(q.z, lz);
        float d = __fadd_rn(__fadd_rn(__fmul_rn(dx, dx), __fmul_rn(dy, dy)),
                            __fmul_rn(dz, dz));
        float nd = fminf(dd[pos], d);
        dd[pos] = nd;
        unsigned long long key =
            ((unsigned long long)__float_as_uint(nd) << 32) |
            (unsigned int)(~__float_as_int(q.w));
#pragma unroll
        for (int off = 32; off >= 1; off >>= 1) {
          unsigned long long ok = __shfl_xor(key, off);
          key = (ok > key) ? ok : key;
        }
        if (lane == 0) {
          s_key[c] = key;
          s_ddmax[c] = __uint_as_float((unsigned int)(key >> 32));
        }
      }
    }
    __syncthreads();  // B2: keys/ddmax ready
    // phase 3: argmax over 256 persistent chunk keys
    unsigned long long k2 = (t < NCH) ? s_key[t] : 0ull;
#pragma unroll
    for (int off = 32; off >= 1; off >>= 1) {
      unsigned long long ok = __shfl_xor(k2, off);
      k2 = (ok > k2) ? ok : k2;
    }
    if (lane == 0) s_wkey[buf][wave] = k2;
    __syncthreads();  // B3: wave partials ready
    unsigned long long kk = s_wkey[buf][lane & 15];
#pragma unroll
    for (int off = 8; off >= 1; off >>= 1) {
      unsigned long long ok = __shfl_xor(kk, off);
      kk = (ok > kk) ? ok : kk;
    }
    int gi = (int)(~(unsigned int)kk);
    lx = p[3 * gi]; ly = p[3 * gi + 1]; lz = p[3 * gi + 2];
    if (t == 0) {
      sidx[i] = gi;
      np_out[3 * i] = lx; np_out[3 * i + 1] = ly; np_out[3 * i + 2] = lz;
    }
  }
}

// ---------------- kNN + grouping + maxpool features: one wave per query ----
__global__ __launch_bounds__(256) void knn_feat_kernel(const float* __restrict__ p,
                                                       const float* __restrict__ x,
                                                       const float* __restrict__ spn,
                                                       const int* __restrict__ sidx,
                                                       float* __restrict__ feat) {
  __shared__ float cd[4][256];
  __shared__ int ci[4][256];
  __shared__ int cnt[4];
  __shared__ int s_nn[4][KNN];
  const int w = threadIdx.x >> 6;
  const int lane = threadIdx.x & 63;
  const int q = (blockIdx.x << 2) + w;
  const int qi = sidx[q];
  const float qx = p[3 * qi], qy = p[3 * qi + 1], qz = p[3 * qi + 2];
  const float sn = spn[qi];
  if (lane == 0) cnt[w] = 0;
  float lmin = INFINITY;
  for (int it = 0; it < N_PTS / 64; ++it) {
    int j = lane + (it << 6);
    float dot = __fmaf_rn(qz, p[3 * j + 2],
                 __fmaf_rn(qy, p[3 * j + 1], __fmul_rn(qx, p[3 * j])));
    float d2 = __fsub_rn(__fadd_rn(sn, spn[j]), __fmul_rn(2.0f, dot));
    lmin = fminf(lmin, d2);
  }
  float mv = lmin;
  float tau = INFINITY;
#pragma unroll
  for (int r = 0; r < KNN; ++r) {
    float rmin = mv;
#pragma unroll
    for (int off = 32; off >= 1; off >>= 1) rmin = fminf(rmin, __shfl_xor(rmin, off));
    tau = rmin;
    unsigned long long msk = __ballot(mv == rmin);
    if (lane == (int)(__ffsll(msk) - 1)) mv = INFINITY;
  }
  __syncthreads();
  for (int it = 0; it < N_PTS / 64; ++it) {
    int j = lane + (it << 6);
    float dot = __fmaf_rn(qz, p[3 * j + 2],
                 __fmaf_rn(qy, p[3 * j + 1], __fmul_rn(qx, p[3 * j])));
    float d2 = __fsub_rn(__fadd_rn(sn, spn[j]), __fmul_rn(2.0f, dot));
    if (d2 <= tau) {
      int pos = atomicAdd(&cnt[w], 1);
      if (pos < 256) { cd[w][pos] = d2; ci[w][pos] = j; }
    }
  }
  __syncthreads();
  int C = min(cnt[w], 256);
  float vv[4]; int ii[4];
#pragma unroll
  for (int s = 0; s < 4; ++s) {
    int pos = lane + (s << 6);
    bool ok = pos < C;
    vv[s] = ok ? cd[w][pos] : INFINITY;
    ii[s] = ok ? ci[w][pos] : 0x7FFFFFFF;
  }
#pragma unroll
  for (int r = 0; r < KNN; ++r) {
    float bv = vv[0]; int bi = ii[0]; int bs = 0;
#pragma unroll
    for (int s = 1; s < 4; ++s) {
      bool tk = (vv[s] < bv) || (vv[s] == bv && ii[s] < bi);
      bv = tk ? vv[s] : bv; bi = tk ? ii[s] : bi; bs = tk ? s : bs;
    }
    float rv = bv; int ri = bi;
#pragma unroll
    for (int off = 32; off >= 1; off >>= 1) {
      float ov = __shfl_xor(rv, off); int oi = __shfl_xor(ri, off);
      bool tk = (ov < rv) || (ov == rv && oi < ri);
      rv = tk ? ov : rv; ri = tk ? oi : ri;
    }
    if (bi == ri) {
#pragma unroll
      for (int s = 0; s < 4; ++s) if (s == bs) vv[s] = INFINITY;
    }
    if (lane == 0) s_nn[w][r] = ri;
  }
  __syncthreads();
  float ax = -INFINITY, ay = -INFINITY, az = -INFINITY, nr = -INFINITY;
  if (lane < KNN) {
    int jn = s_nn[w][lane];
    ax = __fsub_rn(p[3 * jn], qx);
    ay = __fsub_rn(p[3 * jn + 1], qy);
    az = __fsub_rn(p[3 * jn + 2], qz);
    nr = sqrtf(__fadd_rn(__fadd_rn(__fmul_rn(ax, ax), __fmul_rn(ay, ay)),
                         __fmul_rn(az, az)));
  }
  float mnr = nr, mx = ax, my = ay, mz = az;
#pragma unroll
  for (int off = 32; off >= 1; off >>= 1) {
    mnr = fmaxf(mnr, __shfl_xor(mnr, off));
    mx = fmaxf(mx, __shfl_xor(mx, off));
    my = fmaxf(my, __shfl_xor(my, off));
    mz = fmaxf(mz, __shfl_xor(mz, off));
  }
  if (lane == 0) {
    float sden = __fadd_rn(mnr, 1e-8f);
    feat[q * DF + 0] = mx / sden;
    feat[q * DF + 1] = my / sden;
    feat[q * DF + 2] = mz / sden;
  }
  float fm = -INFINITY;
#pragma unroll
  for (int k = 0; k < KNN; ++k) {
    int jn = s_nn[w][k];
    fm = fmaxf(fm, x[(jn << 6) + lane]);
  }
  feat[q * DF + 3 + lane] = fm;
}

// ---------------- MLP: h = feat @ W + b ----------------
__global__ __launch_bounds__(128) void mlp_kernel(const float* __restrict__ feat,
                                                  const float* __restrict__ W,
                                                  const float* __restrict__ b,
                                                  float* __restrict__ h) {
  int mrow = blockIdx.x;
  int o = threadIdx.x;
  const float* fr = feat + mrow * DF;
  float acc = b[o];
#pragma unroll
  for (int k = 0; k < DF; ++k) acc = __fmaf_rn(fr[k], W[k * D_OUTF + o], acc);
  h[mrow * D_OUTF + o] = acc;
}

// ---------------- BN column stats (training mode) ----------------
__global__ __launch_bounds__(256) void stats_kernel(const float* __restrict__ h,
                                                    const float* __restrict__ gamma,
                                                    const float* __restrict__ beta,
                                                    float* __restrict__ scsh) {
  int o = blockIdx.x;
  int t = threadIdx.x;
  float s = 0.f, s2 = 0.f;
  for (int mrow = t; mrow < M_PTS; mrow += 256) {
    float v = h[mrow * D_OUTF + o];
    s += v;
    s2 = __fmaf_rn(v, v, s2);
  }
#pragma unroll
  for (int off = 32; off >= 1; off >>= 1) {
    s += __shfl_xor(s, off);
    s2 += __shfl_xor(s2, off);
  }
  __shared__ float as1[4], as2[4];
  if ((t & 63) == 0) { as1[t >> 6] = s; as2[t >> 6] = s2; }
  __syncthreads();
  if (t == 0) {
    float ts = ((as1[0] + as1[1]) + as1[2]) + as1[3];
    float ts2 = ((as2[0] + as2[1]) + as2[2]) + as2[3];
    float mean = ts / (float)M_PTS;
    float var = ts2 / (float)M_PTS - mean * mean;
    var = fmaxf(var, 0.f);
    float sc = gamma[o] / sqrtf(var + 1e-5f);
    scsh[o] = sc;
    scsh[D_OUTF + o] = beta[o] - mean * sc;
  }
}

// ---------------- BN apply + ReLU + n_o ----------------
__global__ __launch_bounds__(256) void bn_kernel(const float* __restrict__ h,
                                                 const float* __restrict__ scsh,
                                                 float* __restrict__ out) {
  int idx = blockIdx.x * 256 + threadIdx.x;
  int o = idx & (D_OUTF - 1);
  float v = __fmaf_rn(h[idx], scsh[o], scsh[D_OUTF + o]);
  out[M_PTS * 3 + idx] = fmaxf(v, 0.f);
  if (idx == 0) out[M_PTS * 3 + M_PTS * D_OUTF] = 4096.0f;  // n_o
}

extern "C" void kernel_launch(void* const* d_in, const int* in_sizes, int n_in,
                              void* d_out, int out_size, void* d_ws, size_t ws_size,
                              hipStream_t stream) {
  const float* p     = (const float*)d_in[0];
  const float* x     = (const float*)d_in[1];
  // d_in[2] = o (offsets) — unused, single cloud
  const float* W     = (const float*)d_in[3];
  const float* b     = (const float*)d_in[4];
  const float* gamma = (const float*)d_in[5];
  const float* beta  = (const float*)d_in[6];
  float* out = (float*)d_out;

  float* wsf  = (float*)d_ws;
  int*   sidx = (int*)d_ws;                    // [4096]
  float* spn  = wsf + 4096;                    // [16384]
  float* feat = spn + N_PTS;                   // [4096 * 67]
  float* h    = feat + M_PTS * DF;             // [4096 * 128]
  float* scsh = h + M_PTS * D_OUTF;            // [256]
  // setup scratch OVERLAYS feat/h (both written only after fps2 completes)
  int*    hist    = (int*)feat;                // [512]
  int*    cellptr = hist + 512;                // [512]
  float4* sp4     = (float4*)h;                // [16384] float4
  float*  chunkbb = h + N_PTS * 4;             // [256*8]
  float*  dd      = chunkbb + NCH * 8;         // [16384]

  sp_kernel<<<N_PTS / 256, 256, 0, stream>>>(p, spn);
  hipMemsetAsync(hist, 0, NCELL * sizeof(int), stream);
  hist_kernel<<<N_PTS / 256, 256, 0, stream>>>(p, hist);
  scan_kernel<<<1, NCELL, 0, stream>>>(hist, cellptr);
  scatter_kernel<<<N_PTS / 256, 256, 0, stream>>>(p, cellptr, sp4);
  bbox_kernel<<<NCH, 64, 0, stream>>>(sp4, chunkbb);
  fps2_kernel<<<1, 1024, 0, stream>>>(p, sp4, chunkbb, dd, sidx, out);
  knn_feat_kernel<<<M_PTS / 4, 256, 0, stream>>>(p, x, spn, sidx, feat);
  mlp_kernel<<<M_PTS, D_OUTF, 0, stream>>>(feat, W, b, h);
  stats_kernel<<<D_OUTF, 256, 0, stream>>>(h, gamma, beta, scsh);
  bn_kernel<<<(M_PTS * D_OUTF) / 256, 256, 0, stream>>>(h, scsh, out);
}

// Round 6
// 10613.586 us; speedup vs baseline: 1.0676x; 1.0676x over previous
//
#include <hip/hip_runtime.h>

#define N_PTS 16384
#define M_PTS 4096
#define D_INF 64
#define D_OUTF 128
#define KNN 16
#define DF 67   // 3 + 64
#define NCH 256      // 256 chunks x 64 points (Morton-sorted)
#define NCELL2 32768 // 32^3 fine Morton cells

// ---------------- squared norms of p, numpy op order ----------------
__global__ __launch_bounds__(256) void sp_kernel(const float* __restrict__ p,
                                                 float* __restrict__ spn) {
  int j = blockIdx.x * 256 + threadIdx.x;
  float a = p[3 * j], b = p[3 * j + 1], c = p[3 * j + 2];
  spn[j] = __fadd_rn(__fadd_rn(__fmul_rn(a, a), __fmul_rn(b, b)), __fmul_rn(c, c));
}

// ---------------- 15-bit fine Morton cell (32^3, width 0.375) -------------
// R5 post-mortem: 8^3 cells made chunks-within-a-cell share identical bboxes
// -> prune never engaged in the dense core. 32^3 makes chunks spatially tight.
__device__ __forceinline__ int cell32_of(float x, float y, float z) {
  int qx = min(max((int)floorf((x + 6.0f) * 2.6666667f), 0), 31);
  int qy = min(max((int)floorf((y + 6.0f) * 2.6666667f), 0), 31);
  int qz = min(max((int)floorf((z + 6.0f) * 2.6666667f), 0), 31);
  int m = (qx & 1) | ((qx & 2) << 2) | ((qx & 4) << 4) | ((qx & 8) << 6) | ((qx & 16) << 8);
  m |= ((qy & 1) << 1) | ((qy & 2) << 3) | ((qy & 4) << 5) | ((qy & 8) << 7) | ((qy & 16) << 9);
  m |= ((qz & 1) << 2) | ((qz & 2) << 4) | ((qz & 4) << 6) | ((qz & 8) << 8) | ((qz & 16) << 10);
  return m;
}

__global__ __launch_bounds__(256) void hist_kernel(const float* __restrict__ p,
                                                   int* __restrict__ hist) {
  int j = blockIdx.x * 256 + threadIdx.x;
  atomicAdd(&hist[cell32_of(p[3 * j], p[3 * j + 1], p[3 * j + 2])], 1);
}

// exclusive scan of 32768 bins: 1024 thr x 32 bins each
__global__ __launch_bounds__(1024) void scan_kernel(const int* __restrict__ hist,
                                                    int* __restrict__ cellptr) {
  int t = threadIdx.x;
  int lane = t & 63, wave = t >> 6;
  int base = t * 32;
  int s = 0;
  for (int k = 0; k < 32; ++k) s += hist[base + k];
  int v = s;
  for (int off = 1; off < 64; off <<= 1) {
    int o = __shfl_up(v, off, 64);
    if (lane >= off) v += o;
  }
  __shared__ int wsum[16];
  if (lane == 63) wsum[wave] = v;
  __syncthreads();
  int woff = 0;
  for (int w = 0; w < wave; ++w) woff += wsum[w];
  int run = woff + v - s;  // exclusive prefix of this thread's range
  for (int k = 0; k < 32; ++k) {
    int hv = hist[base + k];
    cellptr[base + k] = run;
    run += hv;
  }
}

// scatter into Morton order; w carries the original index as bits
__global__ __launch_bounds__(256) void scatter_kernel(const float* __restrict__ p,
                                                      int* __restrict__ cellptr,
                                                      float4* __restrict__ sp4) {
  int j = blockIdx.x * 256 + threadIdx.x;
  float x = p[3 * j], y = p[3 * j + 1], z = p[3 * j + 2];
  int pos = atomicAdd(&cellptr[cell32_of(x, y, z)], 1);
  sp4[pos] = make_float4(x, y, z, __int_as_float(j));
}

// per-chunk bbox of the 64 sorted points
__global__ __launch_bounds__(64) void bbox_kernel(const float4* __restrict__ sp4,
                                                  float* __restrict__ chunkbb) {
  int c = blockIdx.x;
  int lane = threadIdx.x;
  float4 q = sp4[(c << 6) + lane];
  float mnx = q.x, mxx = q.x, mny = q.y, mxy = q.y, mnz = q.z, mxz = q.z;
#pragma unroll
  for (int off = 32; off >= 1; off >>= 1) {
    mnx = fminf(mnx, __shfl_xor(mnx, off)); mxx = fmaxf(mxx, __shfl_xor(mxx, off));
    mny = fminf(mny, __shfl_xor(mny, off)); mxy = fmaxf(mxy, __shfl_xor(mxy, off));
    mnz = fminf(mnz, __shfl_xor(mnz, off)); mxz = fmaxf(mxz, __shfl_xor(mxz, off));
  }
  if (lane == 0) {
    chunkbb[8 * c + 0] = mnx; chunkbb[8 * c + 1] = mny; chunkbb[8 * c + 2] = mnz;
    chunkbb[8 * c + 3] = mxx; chunkbb[8 * c + 4] = mxy; chunkbb[8 * c + 5] = mxz;
  }
}

// ---------------- FPS, pruned, dd in LDS: single block, 1024 thr ----------
// Exact skip: if lb2(center,bbox)*0.9999 >= ddmax_c then every computed d
// strictly exceeds every dd in the chunk (fp32 error ~1ppm << 100ppm margin)
// so min(dd,d)==dd bit-exactly; chunk keys are therefore ALWAYS exact and
// phase-3 selection needs no per-iteration full sweep.
__global__ __launch_bounds__(1024) void fps3_kernel(const float* __restrict__ p,
                                                    const float4* __restrict__ sp4,
                                                    const float* __restrict__ chunkbb,
                                                    int* __restrict__ sidx,
                                                    float* __restrict__ np_out) {
  const int t = threadIdx.x;
  const int lane = t & 63;
  const int wave = t >> 6;
  __shared__ float s_dd[N_PTS];                    // 64 KB: per-point dists
  __shared__ float s_bb[NCH * 9];                  // stride 9: bank-friendly
  __shared__ float s_ddmax[NCH];
  __shared__ unsigned long long s_key[NCH];        // persistent (ddmax, ~oidx)
  __shared__ float s_cx[NCH], s_cy[NCH], s_cz[NCH];// persistent winner coords
  __shared__ unsigned short s_dirty[NCH];
  __shared__ int s_cnt[2];
  __shared__ unsigned long long s_wkey[2][16];
  __shared__ int s_wcid[2][16];

  for (int j = t; j < N_PTS; j += 1024) s_dd[j] = INFINITY;
  if (t < NCH) {
#pragma unroll
    for (int k = 0; k < 6; ++k) s_bb[9 * t + k] = chunkbb[8 * t + k];
    s_ddmax[t] = INFINITY;
  }
  float lx = p[0], ly = p[1], lz = p[2];  // first center = point 0
  if (t == 0) {
    s_cnt[0] = 0; s_cnt[1] = 0;
    sidx[0] = 0;
    np_out[0] = lx; np_out[1] = ly; np_out[2] = lz;
  }
  __syncthreads();

  for (int i = 1; i < M_PTS; ++i) {
    const int buf = i & 1;
    // phase 1: chunk prune test (256 threads)
    if (t < NCH) {
      float ax = fmaxf(fmaxf(__fsub_rn(s_bb[9 * t + 0], lx),
                             __fsub_rn(lx, s_bb[9 * t + 3])), 0.f);
      float ay = fmaxf(fmaxf(__fsub_rn(s_bb[9 * t + 1], ly),
                             __fsub_rn(ly, s_bb[9 * t + 4])), 0.f);
      float az = fmaxf(fmaxf(__fsub_rn(s_bb[9 * t + 2], lz),
                             __fsub_rn(lz, s_bb[9 * t + 5])), 0.f);
      float lb2 = __fadd_rn(__fadd_rn(__fmul_rn(ax, ax), __fmul_rn(ay, ay)),
                            __fmul_rn(az, az));
      if (__fmul_rn(lb2, 0.9999f) < s_ddmax[t]) {
        int pos = atomicAdd(&s_cnt[buf], 1);
        s_dirty[pos] = (unsigned short)t;
      }
    }
    __syncthreads();  // B1: dirty list ready
    const int cnt = s_cnt[buf];
    if (t == 0) s_cnt[buf ^ 1] = 0;  // prep next iter's counter
    // phase 2: update dirty chunks, one wave per chunk
    const int rounds = (cnt + 15) >> 4;
    for (int r = 0; r < rounds; ++r) {
      int li = (r << 4) + wave;
      if (li < cnt) {
        int c = s_dirty[li];
        int pos = (c << 6) + lane;
        float4 q = sp4[pos];
        float dx = __fsub_rn(q.x, lx);
        float dy = __fsub_rn(q.y, ly);
        float dz = __fsub_rn(q.z, lz);
        float d = __fadd_rn(__fadd_rn(__fmul_rn(dx, dx), __fmul_rn(dy, dy)),
                            __fmul_rn(dz, dz));
        float nd = fminf(s_dd[pos], d);
        s_dd[pos] = nd;
        unsigned long long mykey =
            ((unsigned long long)__float_as_uint(nd) << 32) |
            (unsigned int)(~__float_as_int(q.w));
        unsigned long long key = mykey;
#pragma unroll
        for (int off = 32; off >= 1; off >>= 1) {
          unsigned long long ok = __shfl_xor(key, off);
          key = (ok > key) ? ok : key;
        }
        if (key == mykey) {  // unique winner lane caches its coords
          s_cx[c] = q.x; s_cy[c] = q.y; s_cz[c] = q.z;
        }
        if (lane == 0) {
          s_key[c] = key;
          s_ddmax[c] = __uint_as_float((unsigned int)(key >> 32));
        }
      }
    }
    __syncthreads();  // B2: keys/ddmax/coords ready
    // phase 3: argmax over 256 persistent chunk keys, carrying chunk id
    unsigned long long k2 = (t < NCH) ? s_key[t] : 0ull;
    int c2 = t & (NCH - 1);
#pragma unroll
    for (int off = 32; off >= 1; off >>= 1) {
      unsigned long long ok = __shfl_xor(k2, off);
      int oc = __shfl_xor(c2, off);
      if (ok > k2) { k2 = ok; c2 = oc; }
    }
    if (lane == 0) { s_wkey[buf][wave] = k2; s_wcid[buf][wave] = c2; }
    __syncthreads();  // B3: wave partials ready
    unsigned long long kk = s_wkey[buf][lane & 15];
    int cc = s_wcid[buf][lane & 15];
#pragma unroll
    for (int off = 8; off >= 1; off >>= 1) {
      unsigned long long ok = __shfl_xor(kk, off);
      int oc = __shfl_xor(cc, off);
      if (ok > kk) { kk = ok; cc = oc; }
    }
    int gi = (int)(~(unsigned int)kk);
    // winner coords from LDS (chunk-cached) -> no global load on crit path
    lx = s_cx[cc]; ly = s_cy[cc]; lz = s_cz[cc];
    if (t == 0) {
      sidx[i] = gi;
      np_out[3 * i] = lx; np_out[3 * i + 1] = ly; np_out[3 * i + 2] = lz;
    }
  }
}

// ---------------- kNN + grouping + maxpool features: one wave per query ----
__global__ __launch_bounds__(256) void knn_feat_kernel(const float* __restrict__ p,
                                                       const float* __restrict__ x,
                                                       const float* __restrict__ spn,
                                                       const int* __restrict__ sidx,
                                                       float* __restrict__ feat) {
  __shared__ float cd[4][256];
  __shared__ int ci[4][256];
  __shared__ int cnt[4];
  __shared__ int s_nn[4][KNN];
  const int w = threadIdx.x >> 6;
  const int lane = threadIdx.x & 63;
  const int q = (blockIdx.x << 2) + w;
  const int qi = sidx[q];
  const float qx = p[3 * qi], qy = p[3 * qi + 1], qz = p[3 * qi + 2];
  const float sn = spn[qi];
  if (lane == 0) cnt[w] = 0;
  float lmin = INFINITY;
  for (int it = 0; it < N_PTS / 64; ++it) {
    int j = lane + (it << 6);
    float dot = __fmaf_rn(qz, p[3 * j + 2],
                 __fmaf_rn(qy, p[3 * j + 1], __fmul_rn(qx, p[3 * j])));
    float d2 = __fsub_rn(__fadd_rn(sn, spn[j]), __fmul_rn(2.0f, dot));
    lmin = fminf(lmin, d2);
  }
  float mv = lmin;
  float tau = INFINITY;
#pragma unroll
  for (int r = 0; r < KNN; ++r) {
    float rmin = mv;
#pragma unroll
    for (int off = 32; off >= 1; off >>= 1) rmin = fminf(rmin, __shfl_xor(rmin, off));
    tau = rmin;
    unsigned long long msk = __ballot(mv == rmin);
    if (lane == (int)(__ffsll(msk) - 1)) mv = INFINITY;
  }
  __syncthreads();
  for (int it = 0; it < N_PTS / 64; ++it) {
    int j = lane + (it << 6);
    float dot = __fmaf_rn(qz, p[3 * j + 2],
                 __fmaf_rn(qy, p[3 * j + 1], __fmul_rn(qx, p[3 * j])));
    float d2 = __fsub_rn(__fadd_rn(sn, spn[j]), __fmul_rn(2.0f, dot));
    if (d2 <= tau) {
      int pos = atomicAdd(&cnt[w], 1);
      if (pos < 256) { cd[w][pos] = d2; ci[w][pos] = j; }
    }
  }
  __syncthreads();
  int C = min(cnt[w], 256);
  float vv[4]; int ii[4];
#pragma unroll
  for (int s = 0; s < 4; ++s) {
    int pos = lane + (s << 6);
    bool ok = pos < C;
    vv[s] = ok ? cd[w][pos] : INFINITY;
    ii[s] = ok ? ci[w][pos] : 0x7FFFFFFF;
  }
#pragma unroll
  for (int r = 0; r < KNN; ++r) {
    float bv = vv[0]; int bi = ii[0]; int bs = 0;
#pragma unroll
    for (int s = 1; s < 4; ++s) {
      bool tk = (vv[s] < bv) || (vv[s] == bv && ii[s] < bi);
      bv = tk ? vv[s] : bv; bi = tk ? ii[s] : bi; bs = tk ? s : bs;
    }
    float rv = bv; int ri = bi;
#pragma unroll
    for (int off = 32; off >= 1; off >>= 1) {
      float ov = __shfl_xor(rv, off); int oi = __shfl_xor(ri, off);
      bool tk = (ov < rv) || (ov == rv && oi < ri);
      rv = tk ? ov : rv; ri = tk ? oi : ri;
    }
    if (bi == ri) {
#pragma unroll
      for (int s = 0; s < 4; ++s) if (s == bs) vv[s] = INFINITY;
    }
    if (lane == 0) s_nn[w][r] = ri;
  }
  __syncthreads();
  float ax = -INFINITY, ay = -INFINITY, az = -INFINITY, nr = -INFINITY;
  if (lane < KNN) {
    int jn = s_nn[w][lane];
    ax = __fsub_rn(p[3 * jn], qx);
    ay = __fsub_rn(p[3 * jn + 1], qy);
    az = __fsub_rn(p[3 * jn + 2], qz);
    nr = sqrtf(__fadd_rn(__fadd_rn(__fmul_rn(ax, ax), __fmul_rn(ay, ay)),
                         __fmul_rn(az, az)));
  }
  float mnr = nr, mx = ax, my = ay, mz = az;
#pragma unroll
  for (int off = 32; off >= 1; off >>= 1) {
    mnr = fmaxf(mnr, __shfl_xor(mnr, off));
    mx = fmaxf(mx, __shfl_xor(mx, off));
    my = fmaxf(my, __shfl_xor(my, off));
    mz = fmaxf(mz, __shfl_xor(mz, off));
  }
  if (lane == 0) {
    float sden = __fadd_rn(mnr, 1e-8f);
    feat[q * DF + 0] = mx / sden;
    feat[q * DF + 1] = my / sden;
    feat[q * DF + 2] = mz / sden;
  }
  float fm = -INFINITY;
#pragma unroll
  for (int k = 0; k < KNN; ++k) {
    int jn = s_nn[w][k];
    fm = fmaxf(fm, x[(jn << 6) + lane]);
  }
  feat[q * DF + 3 + lane] = fm;
}

// ---------------- MLP: h = feat @ W + b ----------------
__global__ __launch_bounds__(128) void mlp_kernel(const float* __restrict__ feat,
                                                  const float* __restrict__ W,
                                                  const float* __restrict__ b,
                                                  float* __restrict__ h) {
  int mrow = blockIdx.x;
  int o = threadIdx.x;
  const float* fr = feat + mrow * DF;
  float acc = b[o];
#pragma unroll
  for (int k = 0; k < DF; ++k) acc = __fmaf_rn(fr[k], W[k * D_OUTF + o], acc);
  h[mrow * D_OUTF + o] = acc;
}

// ---------------- BN column stats (training mode) ----------------
__global__ __launch_bounds__(256) void stats_kernel(const float* __restrict__ h,
                                                    const float* __restrict__ gamma,
                                                    const float* __restrict__ beta,
                                                    float* __restrict__ scsh) {
  int o = blockIdx.x;
  int t = threadIdx.x;
  float s = 0.f, s2 = 0.f;
  for (int mrow = t; mrow < M_PTS; mrow += 256) {
    float v = h[mrow * D_OUTF + o];
    s += v;
    s2 = __fmaf_rn(v, v, s2);
  }
#pragma unroll
  for (int off = 32; off >= 1; off >>= 1) {
    s += __shfl_xor(s, off);
    s2 += __shfl_xor(s2, off);
  }
  __shared__ float as1[4], as2[4];
  if ((t & 63) == 0) { as1[t >> 6] = s; as2[t >> 6] = s2; }
  __syncthreads();
  if (t == 0) {
    float ts = ((as1[0] + as1[1]) + as1[2]) + as1[3];
    float ts2 = ((as2[0] + as2[1]) + as2[2]) + as2[3];
    float mean = ts / (float)M_PTS;
    float var = ts2 / (float)M_PTS - mean * mean;
    var = fmaxf(var, 0.f);
    float sc = gamma[o] / sqrtf(var + 1e-5f);
    scsh[o] = sc;
    scsh[D_OUTF + o] = beta[o] - mean * sc;
  }
}

// ---------------- BN apply + ReLU + n_o ----------------
__global__ __launch_bounds__(256) void bn_kernel(const float* __restrict__ h,
                                                 const float* __restrict__ scsh,
                                                 float* __restrict__ out) {
  int idx = blockIdx.x * 256 + threadIdx.x;
  int o = idx & (D_OUTF - 1);
  float v = __fmaf_rn(h[idx], scsh[o], scsh[D_OUTF + o]);
  out[M_PTS * 3 + idx] = fmaxf(v, 0.f);
  if (idx == 0) out[M_PTS * 3 + M_PTS * D_OUTF] = 4096.0f;  // n_o
}

extern "C" void kernel_launch(void* const* d_in, const int* in_sizes, int n_in,
                              void* d_out, int out_size, void* d_ws, size_t ws_size,
                              hipStream_t stream) {
  const float* p     = (const float*)d_in[0];
  const float* x     = (const float*)d_in[1];
  // d_in[2] = o (offsets) — unused, single cloud
  const float* W     = (const float*)d_in[3];
  const float* b     = (const float*)d_in[4];
  const float* gamma = (const float*)d_in[5];
  const float* beta  = (const float*)d_in[6];
  float* out = (float*)d_out;

  float* wsf  = (float*)d_ws;
  int*   sidx = (int*)d_ws;                    // [4096]
  float* spn  = wsf + 4096;                    // [16384]
  float* feat = spn + N_PTS;                   // [4096 * 67]
  float* h    = feat + M_PTS * DF;             // [4096 * 128]
  float* scsh = h + M_PTS * D_OUTF;            // [256]
  // setup scratch OVERLAYS feat/h (both written only after fps3 completes)
  int*    hist    = (int*)feat;                // [32768]
  int*    cellptr = hist + NCELL2;             // [32768]  (256 KB < feat's 1 MB)
  float4* sp4     = (float4*)h;                // [16384] float4 (256 KB < h's 2 MB)
  float*  chunkbb = h + N_PTS * 4;             // [256*8]

  sp_kernel<<<N_PTS / 256, 256, 0, stream>>>(p, spn);
  hipMemsetAsync(hist, 0, NCELL2 * sizeof(int), stream);
  hist_kernel<<<N_PTS / 256, 256, 0, stream>>>(p, hist);
  scan_kernel<<<1, 1024, 0, stream>>>(hist, cellptr);
  scatter_kernel<<<N_PTS / 256, 256, 0, stream>>>(p, cellptr, sp4);
  bbox_kernel<<<NCH, 64, 0, stream>>>(sp4, chunkbb);
  fps3_kernel<<<1, 1024, 0, stream>>>(p, sp4, chunkbb, sidx, out);
  knn_feat_kernel<<<M_PTS / 4, 256, 0, stream>>>(p, x, spn, sidx, feat);
  mlp_kernel<<<M_PTS, D_OUTF, 0, stream>>>(feat, W, b, h);
  stats_kernel<<<D_OUTF, 256, 0, stream>>>(h, gamma, beta, scsh);
  bn_kernel<<<(M_PTS * D_OUTF) / 256, 256, 0, stream>>>(h, scsh, out);
}